// Round 4
// baseline (1130.867 us; speedup 1.0000x reference)
//
#include <hip/hip_runtime.h>
#include <cstdint>
#include <cstddef>

#define NN   50000
#define NE   500000
#define DIN  64
#define EDIM 32
#define NH   4
#define NC   64
#define HC   256   // NH*NC
#define NGG  64
#define ND   64
#define LN_EPS 1e-5f

typedef __attribute__((ext_vector_type(8))) short bf16x8;
typedef __attribute__((ext_vector_type(4))) float f32x4;
typedef __attribute__((ext_vector_type(4))) unsigned short u16x4;
typedef __attribute__((ext_vector_type(2))) float v2f;

__device__ __forceinline__ unsigned short f2bf(float x) {
    unsigned u = __float_as_uint(x);
    unsigned r = (u + 0x7FFFu + ((u >> 16) & 1u)) >> 16;
    return (unsigned short)r;
}
__device__ __forceinline__ float bf2f(unsigned short h) {
    return __uint_as_float(((unsigned)h) << 16);
}

// packed fp32 FMA: acc = a*b + acc (two lanes' worth per instruction slot)
__device__ __forceinline__ void pkfma(v2f& acc, v2f a, v2f b) {
    asm("v_pk_fma_f32 %0, %1, %2, %0" : "+v"(acc) : "v"(a), "v"(b));
}

// ---------------------------------------------------------------------------
// CSR build: degree count -> single-block scan -> fill
// ---------------------------------------------------------------------------
__global__ void count_deg(const int* __restrict__ dst, int* __restrict__ deg) {
    int e = blockIdx.x * blockDim.x + threadIdx.x;
    if (e < NE) atomicAdd(&deg[dst[e]], 1);
}

__global__ void scan_deg(int* __restrict__ cursor, int* __restrict__ row_ptr) {
    __shared__ int sums[1024];
    const int T = 1024;
    const int chunk = (NN + T - 1) / T;  // 49
    int t = threadIdx.x;
    int lo = t * chunk, hi = min(lo + chunk, NN);
    int s = 0;
    for (int i = lo; i < hi; i++) s += cursor[i];
    sums[t] = s;
    __syncthreads();
    for (int off = 1; off < T; off <<= 1) {
        int v = (t >= off) ? sums[t - off] : 0;
        __syncthreads();
        sums[t] += v;
        __syncthreads();
    }
    int base = (t == 0) ? 0 : sums[t - 1];
    for (int i = lo; i < hi; i++) {
        int d = cursor[i];
        row_ptr[i] = base;
        cursor[i] = base;
        base += d;
    }
    if (t == 0) row_ptr[NN] = NE;
}

__global__ void fill_csr(const int* __restrict__ src, const int* __restrict__ dst,
                         int* __restrict__ cursor, int* __restrict__ csr_src,
                         int* __restrict__ csr_eid) {
    int e = blockIdx.x * blockDim.x + threadIdx.x;
    if (e < NE) {
        int d = dst[e];
        int pos = atomicAdd(&cursor[d], 1);
        csr_src[pos] = src[e];
        csr_eid[pos] = e;
    }
}

__global__ void loop_attr_kernel(const float* __restrict__ ef, const int* __restrict__ row_ptr,
                                 const int* __restrict__ csr_eid, float* __restrict__ loop_attr) {
    int idx = blockIdx.x * blockDim.x + threadIdx.x;
    if (idx >= NN * EDIM) return;
    int n = idx >> 5, c = idx & 31;
    int s = row_ptr[n], e = row_ptr[n + 1];
    float acc = 0.f;
    for (int j = s; j < e; j++) acc += ef[(size_t)csr_eid[j] * EDIM + c];
    int d = e - s;
    loop_attr[(size_t)n * EDIM + c] = acc / (float)max(d, 1);
}

// ---------------------------------------------------------------------------
// Weight pre-passes
// ---------------------------------------------------------------------------
// W[K][N] fp32 -> transposed bf16 hi/lo [N][K] (for MFMA GEMM)
__global__ void conv_wt(const float* __restrict__ W, unsigned short* __restrict__ hi,
                        unsigned short* __restrict__ lo, int K, int Nn) {
    int idx = blockIdx.x * blockDim.x + threadIdx.x;
    if (idx >= K * Nn) return;
    int k = idx / Nn, n = idx - k * Nn;
    float x = W[idx];
    unsigned short h = f2bf(x);
    unsigned short l = f2bf(x - bf2f(h));
    hi[(size_t)n * K + k] = h;
    lo[(size_t)n * K + k] = l;
}

// We[EDIM][HC] fp32 -> transposed fp32 Wet[HC][EDIM] (for pk_fma edge scoring)
__global__ void conv_we(const float* __restrict__ We, float* __restrict__ Wet) {
    int idx = blockIdx.x * blockDim.x + threadIdx.x;
    if (idx >= EDIM * HC) return;
    int k = idx / HC, c = idx - k * HC;
    Wet[(size_t)c * EDIM + k] = We[idx];
}

// ---------------------------------------------------------------------------
// MFMA split-bf16 GEMM: C[M,Nn] = A[M,K] @ B[K,Nn] + bias.
// ---------------------------------------------------------------------------
#define LDT 40

__global__ __launch_bounds__(256, 2)
void gemm_mfma(const float* __restrict__ A, const unsigned short* __restrict__ Bth,
               const unsigned short* __restrict__ Btl, const float* __restrict__ bias,
               float* __restrict__ C, int M, int K, int Nn) {
    __shared__ unsigned short Ah[64][LDT], Al[64][LDT];
    __shared__ unsigned short Bh[64][LDT], Bl[64][LDT];
    int tid = threadIdx.x;
    int lane = tid & 63, w = tid >> 6;
    int m = lane & 15, q = lane >> 4;
    int rowBase = blockIdx.y * 64, colBase = blockIdx.x * 64;
    f32x4 acc[4];
    #pragma unroll
    for (int ct = 0; ct < 4; ct++) acc[ct] = (f32x4){0.f, 0.f, 0.f, 0.f};

    for (int kk = 0; kk < K; kk += 32) {
        #pragma unroll
        for (int u = 0; u < 2; u++) {
            int f = tid + 256 * u;
            int r = f >> 3;
            int k4 = (f & 7) * 4;
            int row = rowBase + r;
            float4 v = make_float4(0.f, 0.f, 0.f, 0.f);
            if (row < M) v = *(const float4*)(A + (size_t)row * K + kk + k4);
            unsigned short h0 = f2bf(v.x), h1 = f2bf(v.y), h2 = f2bf(v.z), h3 = f2bf(v.w);
            unsigned short l0 = f2bf(v.x - bf2f(h0)), l1 = f2bf(v.y - bf2f(h1));
            unsigned short l2 = f2bf(v.z - bf2f(h2)), l3 = f2bf(v.w - bf2f(h3));
            *(u16x4*)&Ah[r][k4] = (u16x4){h0, h1, h2, h3};
            *(u16x4*)&Al[r][k4] = (u16x4){l0, l1, l2, l3};
        }
        {
            int n = tid >> 2;
            int ch = tid & 3;
            size_t goff = (size_t)(colBase + n) * K + kk + ch * 8;
            *(bf16x8*)&Bh[n][ch * 8] = *(const bf16x8*)(Bth + goff);
            *(bf16x8*)&Bl[n][ch * 8] = *(const bf16x8*)(Btl + goff);
        }
        __syncthreads();
        bf16x8 a_h = *(const bf16x8*)&Ah[w * 16 + m][q * 8];
        bf16x8 a_l = *(const bf16x8*)&Al[w * 16 + m][q * 8];
        #pragma unroll
        for (int ct = 0; ct < 4; ct++) {
            bf16x8 b_h = *(const bf16x8*)&Bh[ct * 16 + m][q * 8];
            bf16x8 b_l = *(const bf16x8*)&Bl[ct * 16 + m][q * 8];
            acc[ct] = __builtin_amdgcn_mfma_f32_16x16x32_bf16(a_h, b_h, acc[ct], 0, 0, 0);
            acc[ct] = __builtin_amdgcn_mfma_f32_16x16x32_bf16(a_l, b_h, acc[ct], 0, 0, 0);
            acc[ct] = __builtin_amdgcn_mfma_f32_16x16x32_bf16(a_h, b_l, acc[ct], 0, 0, 0);
        }
        __syncthreads();
    }
    #pragma unroll
    for (int ct = 0; ct < 4; ct++) {
        int col = colBase + ct * 16 + m;
        float bb = bias[col];
        #pragma unroll
        for (int r = 0; r < 4; r++) {
            int row = rowBase + w * 16 + q * 4 + r;
            if (row < M) C[(size_t)row * Nn + col] = acc[ct][r] + bb;
        }
    }
}

// ---------------------------------------------------------------------------
// Fused GATv2 attention + online-softmax aggregation.
// We pre-transposed to Wet[HC][EDIM] fp32; each lane holds its 4 channels'
// rows as 64 v2f (128 VGPRs), pinned via empty asm so the compiler cannot
// rematerialize the loads. ee dot via v_pk_fma_f32 (2 MACs/instr).
// ---------------------------------------------------------------------------
__device__ __forceinline__ void load_ea2(const float* __restrict__ p, v2f ea2[16]) {
    #pragma unroll
    for (int q = 0; q < 8; q++) {
        float4 t = *(const float4*)(p + 4 * q);
        ea2[2 * q] = (v2f){t.x, t.y};
        ea2[2 * q + 1] = (v2f){t.z, t.w};
    }
}

__device__ __forceinline__ float gat_score_pk(const v2f ea2[16], const v2f wr[64],
                                              float4 xlv, float4 xrv, float4 attv) {
    v2f a0 = (v2f){0.f, 0.f}, a1 = (v2f){0.f, 0.f};
    v2f a2 = (v2f){0.f, 0.f}, a3 = (v2f){0.f, 0.f};
    #pragma unroll
    for (int pp = 0; pp < 16; pp++) {
        pkfma(a0, ea2[pp], wr[pp]);
        pkfma(a1, ea2[pp], wr[16 + pp]);
        pkfma(a2, ea2[pp], wr[32 + pp]);
        pkfma(a3, ea2[pp], wr[48 + pp]);
    }
    float m0 = xlv.x + xrv.x + a0.x + a0.y; m0 = m0 > 0.f ? m0 : 0.2f * m0;
    float m1 = xlv.y + xrv.y + a1.x + a1.y; m1 = m1 > 0.f ? m1 : 0.2f * m1;
    float m2 = xlv.z + xrv.z + a2.x + a2.y; m2 = m2 > 0.f ? m2 : 0.2f * m2;
    float m3 = xlv.w + xrv.w + a3.x + a3.y; m3 = m3 > 0.f ? m3 : 0.2f * m3;
    float p = m0 * attv.x + m1 * attv.y + m2 * attv.z + m3 * attv.w;
    p += __shfl_xor(p, 1);
    p += __shfl_xor(p, 2);
    p += __shfl_xor(p, 4);
    p += __shfl_xor(p, 8);
    return p;
}

__global__ __launch_bounds__(256, 2)
void gat_fused(const float* __restrict__ xl, const float* __restrict__ xr,
               const float* __restrict__ ef, const float* __restrict__ loop_attr,
               const int* __restrict__ row_ptr, const int* __restrict__ csr_src,
               const int* __restrict__ csr_eid,
               const float* __restrict__ Wet, const float* __restrict__ att,
               const float* __restrict__ bias, float* __restrict__ out, int do_relu) {
    int lane = threadIdx.x & 63;
    int wv = threadIdx.x >> 6;
    int wid = blockIdx.x * 4 + wv;
    int nw = gridDim.x * 4;

    // Load this lane's 4 channel-rows of Wet (fp32) as v2f pairs.
    v2f wr[64];
    #pragma unroll
    for (int ch = 0; ch < 4; ch++) {
        #pragma unroll
        for (int j = 0; j < 8; j++) {
            float4 t = *(const float4*)(Wet + (size_t)(4 * lane + ch) * EDIM + 4 * j);
            wr[ch * 16 + 2 * j] = (v2f){t.x, t.y};
            wr[ch * 16 + 2 * j + 1] = (v2f){t.z, t.w};
        }
    }
    // Pin: values now defined by asm -> cannot be rematerialized by reloading.
    #pragma unroll
    for (int i = 0; i < 64; i++) asm volatile("" : "+v"(wr[i]));

    int h = lane >> 4;
    float4 attv = *(const float4*)(att + h * NC + 4 * (lane & 15));
    float4 bb = *(const float4*)(bias + 4 * lane);

    for (int n0 = wid; n0 < NN; n0 += nw) {
        int n = __builtin_amdgcn_readfirstlane(n0);
        float4 xrv = *(const float4*)(xr + (size_t)n * HC + 4 * lane);
        int s0 = row_ptr[n], e0 = row_ptr[n + 1];

        // ---- self-loop ----
        v2f ea2[16];
        load_ea2(loop_attr + (size_t)n * EDIM, ea2);
        float4 xlv = *(const float4*)(xl + (size_t)n * HC + 4 * lane);
        float p = gat_score_pk(ea2, wr, xlv, xrv, attv);
        float mx = p;
        float denom = 1.f;
        float4 acc = xlv;

        // ---- edges, unrolled x2 ----
        int j = s0;
        for (; j + 1 < e0; j += 2) {
            int sa = __builtin_amdgcn_readfirstlane(csr_src[j]);
            int sb = __builtin_amdgcn_readfirstlane(csr_src[j + 1]);
            int ia = __builtin_amdgcn_readfirstlane(csr_eid[j]);
            int ib = __builtin_amdgcn_readfirstlane(csr_eid[j + 1]);
            v2f eaA[16], eaB[16];
            load_ea2(ef + (size_t)ia * EDIM, eaA);
            load_ea2(ef + (size_t)ib * EDIM, eaB);
            float4 xla = *(const float4*)(xl + (size_t)sa * HC + 4 * lane);
            float4 xlb = *(const float4*)(xl + (size_t)sb * HC + 4 * lane);
            float pa = gat_score_pk(eaA, wr, xla, xrv, attv);
            float pb = gat_score_pk(eaB, wr, xlb, xrv, attv);
            float nm = fmaxf(mx, pa);
            float sc = __expf(mx - nm);
            float aa = __expf(pa - nm);
            denom = denom * sc + aa;
            acc.x = acc.x * sc + xla.x * aa; acc.y = acc.y * sc + xla.y * aa;
            acc.z = acc.z * sc + xla.z * aa; acc.w = acc.w * sc + xla.w * aa;
            mx = nm;
            nm = fmaxf(mx, pb);
            sc = __expf(mx - nm);
            aa = __expf(pb - nm);
            denom = denom * sc + aa;
            acc.x = acc.x * sc + xlb.x * aa; acc.y = acc.y * sc + xlb.y * aa;
            acc.z = acc.z * sc + xlb.z * aa; acc.w = acc.w * sc + xlb.w * aa;
            mx = nm;
        }
        if (j < e0) {
            int sa = __builtin_amdgcn_readfirstlane(csr_src[j]);
            int ia = __builtin_amdgcn_readfirstlane(csr_eid[j]);
            v2f eaA[16];
            load_ea2(ef + (size_t)ia * EDIM, eaA);
            float4 xla = *(const float4*)(xl + (size_t)sa * HC + 4 * lane);
            float pa = gat_score_pk(eaA, wr, xla, xrv, attv);
            float nm = fmaxf(mx, pa);
            float sc = __expf(mx - nm);
            float aa = __expf(pa - nm);
            denom = denom * sc + aa;
            acc.x = acc.x * sc + xla.x * aa; acc.y = acc.y * sc + xla.y * aa;
            acc.z = acc.z * sc + xla.z * aa; acc.w = acc.w * sc + xla.w * aa;
            mx = nm;
        }

        float inv = 1.f / denom;
        float4 r = make_float4(acc.x * inv + bb.x, acc.y * inv + bb.y,
                               acc.z * inv + bb.z, acc.w * inv + bb.w);
        if (do_relu) {
            r.x = fmaxf(r.x, 0.f); r.y = fmaxf(r.y, 0.f);
            r.z = fmaxf(r.z, 0.f); r.w = fmaxf(r.w, 0.f);
        }
        *(float4*)(out + (size_t)n * HC + 4 * lane) = r;
    }
}

// ---------------------------------------------------------------------------
// In-place LayerNorm over rows of width 64 (one wave per row)
// ---------------------------------------------------------------------------
__global__ void ln_rows(float* __restrict__ y, const float* __restrict__ g,
                        const float* __restrict__ b, int M) {
    int lane = threadIdx.x & 63;
    int wv = threadIdx.x >> 6;
    int n = blockIdx.x * 4 + wv;
    if (n >= M) return;
    float v = y[(size_t)n * 64 + lane];
    float s = v;
    #pragma unroll
    for (int o = 32; o >= 1; o >>= 1) s += __shfl_xor(s, o);
    float mu = s * (1.f / 64.f);
    float dv = v - mu;
    float q = dv * dv;
    #pragma unroll
    for (int o = 32; o >= 1; o >>= 1) q += __shfl_xor(q, o);
    float var = q * (1.f / 64.f);
    y[(size_t)n * 64 + lane] = dv * rsqrtf(var + LN_EPS) * g[lane] + b[lane];
}

// ---------------------------------------------------------------------------
// Graph mean pre-reduction exploiting sorted batch
// ---------------------------------------------------------------------------
__global__ void graph_sum(const float* __restrict__ x, const int* __restrict__ batch,
                          float* __restrict__ gsum, float* __restrict__ gcnt) {
    int c = threadIdx.x;
    int r0 = blockIdx.x * 256;
    int r1 = min(r0 + 256, NN);
    float acc = 0.f;
    int gcur = batch[r0];
    for (int n = r0; n < r1; n++) {
        int g = batch[n];
        if (g != gcur) {
            atomicAdd(&gsum[(size_t)gcur * HC + c], acc);
            acc = 0.f; gcur = g;
        }
        acc += x[(size_t)n * HC + c];
    }
    atomicAdd(&gsum[(size_t)gcur * HC + c], acc);
    if (c == 0) {
        int cnt = 0; gcur = batch[r0];
        for (int n = r0; n < r1; n++) {
            int g = batch[n];
            if (g != gcur) {
                atomicAdd(&gcnt[gcur], (float)cnt);
                cnt = 0; gcur = g;
            }
            cnt++;
        }
        atomicAdd(&gcnt[gcur], (float)cnt);
    }
}

__global__ void glob_kernel(const float* __restrict__ gsum, const float* __restrict__ gcnt,
                            const float* __restrict__ W, const float* __restrict__ bias,
                            const float* __restrict__ g, const float* __restrict__ b,
                            float* __restrict__ out) {
    int gi = blockIdx.x;
    int lane = threadIdx.x;
    float inv = 1.f / fmaxf(gcnt[gi], 1.f);
    float acc = 0.f;
    for (int k = 0; k < HC; k++)
        acc += (gsum[(size_t)gi * HC + k] * inv) * W[(size_t)k * ND + lane];
    acc += bias[lane];
    float s = acc;
    #pragma unroll
    for (int o = 32; o >= 1; o >>= 1) s += __shfl_xor(s, o);
    float mu = s * (1.f / 64.f);
    float dv = acc - mu;
    float q = dv * dv;
    #pragma unroll
    for (int o = 32; o >= 1; o >>= 1) q += __shfl_xor(q, o);
    float var = q * (1.f / 64.f);
    out[(size_t)gi * ND + lane] = dv * rsqrtf(var + LN_EPS) * g[lane] + b[lane];
}

// ---------------------------------------------------------------------------
extern "C" void kernel_launch(void* const* d_in, const int* in_sizes, int n_in,
                              void* d_out, int out_size, void* d_ws, size_t ws_size,
                              hipStream_t stream) {
    (void)in_sizes; (void)n_in; (void)out_size; (void)ws_size;
    const float* node_feature = (const float*)d_in[0];
    const int*   edge_index   = (const int*)d_in[1];
    const float* edge_feature = (const float*)d_in[2];
    const int*   batch        = (const int*)d_in[3];
    const float* Wl0   = (const float*)d_in[4];
    const float* bl0   = (const float*)d_in[5];
    const float* Wr0   = (const float*)d_in[6];
    const float* br0   = (const float*)d_in[7];
    const float* We0   = (const float*)d_in[8];
    const float* att0  = (const float*)d_in[9];
    const float* bias0 = (const float*)d_in[10];
    const float* Wl1   = (const float*)d_in[11];
    const float* bl1   = (const float*)d_in[12];
    const float* Wr1   = (const float*)d_in[13];
    const float* br1   = (const float*)d_in[14];
    const float* We1   = (const float*)d_in[15];
    const float* att1  = (const float*)d_in[16];
    const float* bias1 = (const float*)d_in[17];
    const float* node_W  = (const float*)d_in[18];
    const float* node_b  = (const float*)d_in[19];
    const float* graph_W = (const float*)d_in[20];
    const float* graph_b = (const float*)d_in[21];
    const float* nn_g = (const float*)d_in[22];
    const float* nn_b = (const float*)d_in[23];
    const float* gn_g = (const float*)d_in[24];
    const float* gn_b = (const float*)d_in[25];

    const int* src = edge_index;
    const int* dst = edge_index + NE;

    char* p = (char*)d_ws;
    auto carve = [&](size_t bytes) {
        char* r = p;
        p += (bytes + 255) & ~(size_t)255;
        return r;
    };
    int*   row_ptr   = (int*)carve((NN + 1) * sizeof(int));
    int*   cursor    = (int*)carve(NN * sizeof(int));
    int*   csr_src   = (int*)carve((size_t)NE * sizeof(int));
    int*   csr_eid   = (int*)carve((size_t)NE * sizeof(int));
    float* loop_attr = (float*)carve((size_t)NN * EDIM * sizeof(float));
    float* xl        = (float*)carve((size_t)NN * HC * sizeof(float));
    float* xr        = (float*)carve((size_t)NN * HC * sizeof(float));
    float* xb        = (float*)carve((size_t)NN * HC * sizeof(float));
    float* gsum      = (float*)carve((size_t)(NGG * HC + NGG) * sizeof(float));
    float* gcnt      = gsum + (size_t)NGG * HC;
    // bf16 transposed weight buffers (hi/lo)
    unsigned short* wl0h = (unsigned short*)carve((size_t)DIN * HC * 2 * 2);
    unsigned short* wl0l = wl0h + (size_t)DIN * HC;
    unsigned short* wr0h = (unsigned short*)carve((size_t)DIN * HC * 2 * 2);
    unsigned short* wr0l = wr0h + (size_t)DIN * HC;
    unsigned short* wl1h = (unsigned short*)carve((size_t)HC * HC * 2 * 2);
    unsigned short* wl1l = wl1h + (size_t)HC * HC;
    unsigned short* wr1h = (unsigned short*)carve((size_t)HC * HC * 2 * 2);
    unsigned short* wr1l = wr1h + (size_t)HC * HC;
    unsigned short* nwh  = (unsigned short*)carve((size_t)HC * ND * 2 * 2);
    unsigned short* nwl  = nwh + (size_t)HC * ND;
    // transposed fp32 We for edge scoring
    float* wet0 = (float*)carve((size_t)EDIM * HC * sizeof(float));
    float* wet1 = (float*)carve((size_t)EDIM * HC * sizeof(float));

    hipMemsetAsync(cursor, 0, NN * sizeof(int), stream);
    hipMemsetAsync(gsum, 0, (NGG * HC + NGG) * sizeof(float), stream);

    // CSR + loop_attr + weight conversion (layer-independent)
    count_deg<<<(NE + 255) / 256, 256, 0, stream>>>(dst, cursor);
    scan_deg<<<1, 1024, 0, stream>>>(cursor, row_ptr);
    fill_csr<<<(NE + 255) / 256, 256, 0, stream>>>(src, dst, cursor, csr_src, csr_eid);
    loop_attr_kernel<<<(NN * EDIM + 255) / 256, 256, 0, stream>>>(edge_feature, row_ptr, csr_eid, loop_attr);
    conv_wt<<<(DIN * HC + 255) / 256, 256, 0, stream>>>(Wl0, wl0h, wl0l, DIN, HC);
    conv_wt<<<(DIN * HC + 255) / 256, 256, 0, stream>>>(Wr0, wr0h, wr0l, DIN, HC);
    conv_wt<<<(HC * HC + 255) / 256, 256, 0, stream>>>(Wl1, wl1h, wl1l, HC, HC);
    conv_wt<<<(HC * HC + 255) / 256, 256, 0, stream>>>(Wr1, wr1h, wr1l, HC, HC);
    conv_wt<<<(HC * ND + 255) / 256, 256, 0, stream>>>(node_W, nwh, nwl, HC, ND);
    conv_we<<<(EDIM * HC + 255) / 256, 256, 0, stream>>>(We0, wet0);
    conv_we<<<(EDIM * HC + 255) / 256, 256, 0, stream>>>(We1, wet1);

    dim3 g256(HC / 64, (NN + 63) / 64);
    dim3 g64(ND / 64, (NN + 63) / 64);
    // Layer 0
    gemm_mfma<<<g256, 256, 0, stream>>>(node_feature, wl0h, wl0l, bl0, xl, NN, DIN, HC);
    gemm_mfma<<<g256, 256, 0, stream>>>(node_feature, wr0h, wr0l, br0, xr, NN, DIN, HC);
    gat_fused<<<2048, 256, 0, stream>>>(xl, xr, edge_feature, loop_attr, row_ptr, csr_src, csr_eid,
                                        wet0, att0, bias0, xb, 1);
    // Layer 1
    gemm_mfma<<<g256, 256, 0, stream>>>(xb, wl1h, wl1l, bl1, xl, NN, HC, HC);
    gemm_mfma<<<g256, 256, 0, stream>>>(xb, wr1h, wr1l, br1, xr, NN, HC, HC);
    gat_fused<<<2048, 256, 0, stream>>>(xl, xr, edge_feature, loop_attr, row_ptr, csr_src, csr_eid,
                                        wet1, att1, bias1, xb, 0);

    // Heads
    float* out_local = (float*)d_out;
    float* out_glob  = out_local + (size_t)NN * ND;
    gemm_mfma<<<g64, 256, 0, stream>>>(xb, nwh, nwl, node_b, out_local, NN, HC, ND);
    ln_rows<<<(NN + 3) / 4, 256, 0, stream>>>(out_local, nn_g, nn_b, NN);
    graph_sum<<<(NN + 255) / 256, 256, 0, stream>>>(xb, batch, gsum, gcnt);
    glob_kernel<<<NGG, 64, 0, stream>>>(gsum, gcnt, graph_W, graph_b, gn_g, gn_b, out_glob);
}

// Round 6
// 1015.942 us; speedup vs baseline: 1.1131x; 1.1131x over previous
//
#include <hip/hip_runtime.h>
#include <cstdint>
#include <cstddef>

#define NN   50000
#define NE   500000
#define DIN  64
#define EDIM 32
#define NH   4
#define NC   64
#define HC   256   // NH*NC
#define NGG  64
#define ND   64
#define LN_EPS 1e-5f
#define EESLOTS (NE + NN)   // edges + self-loops, CSR-slot order

typedef __attribute__((ext_vector_type(8))) short bf16x8;
typedef __attribute__((ext_vector_type(4))) float f32x4;
typedef __attribute__((ext_vector_type(4))) unsigned short u16x4;

__device__ __forceinline__ unsigned short f2bf(float x) {
    unsigned u = __float_as_uint(x);
    unsigned r = (u + 0x7FFFu + ((u >> 16) & 1u)) >> 16;
    return (unsigned short)r;
}
__device__ __forceinline__ float bf2f(unsigned short h) {
    return __uint_as_float(((unsigned)h) << 16);
}

// ---------------------------------------------------------------------------
// CSR build: degree count -> single-block scan -> fill
// ---------------------------------------------------------------------------
__global__ void count_deg(const int* __restrict__ dst, int* __restrict__ deg) {
    int e = blockIdx.x * blockDim.x + threadIdx.x;
    if (e < NE) atomicAdd(&deg[dst[e]], 1);
}

__global__ void scan_deg(int* __restrict__ cursor, int* __restrict__ row_ptr) {
    __shared__ int sums[1024];
    const int T = 1024;
    const int chunk = (NN + T - 1) / T;  // 49
    int t = threadIdx.x;
    int lo = t * chunk, hi = min(lo + chunk, NN);
    int s = 0;
    for (int i = lo; i < hi; i++) s += cursor[i];
    sums[t] = s;
    __syncthreads();
    for (int off = 1; off < T; off <<= 1) {
        int v = (t >= off) ? sums[t - off] : 0;
        __syncthreads();
        sums[t] += v;
        __syncthreads();
    }
    int base = (t == 0) ? 0 : sums[t - 1];
    for (int i = lo; i < hi; i++) {
        int d = cursor[i];
        row_ptr[i] = base;
        cursor[i] = base;
        base += d;
    }
    if (t == 0) row_ptr[NN] = NE;
}

__global__ void fill_csr(const int* __restrict__ src, const int* __restrict__ dst,
                         int* __restrict__ cursor, int* __restrict__ csr_src,
                         int* __restrict__ csr_dst, int* __restrict__ csr_eid) {
    int e = blockIdx.x * blockDim.x + threadIdx.x;
    if (e < NE) {
        int d = dst[e];
        int pos = atomicAdd(&cursor[d], 1);
        csr_src[pos] = src[e];
        csr_dst[pos] = d;
        csr_eid[pos] = e;
    }
}

__global__ void loop_attr_kernel(const float* __restrict__ ef, const int* __restrict__ row_ptr,
                                 const int* __restrict__ csr_eid, float* __restrict__ loop_attr) {
    int idx = blockIdx.x * blockDim.x + threadIdx.x;
    if (idx >= NN * EDIM) return;
    int n = idx >> 5, c = idx & 31;
    int s = row_ptr[n], e = row_ptr[n + 1];
    float acc = 0.f;
    for (int j = s; j < e; j++) acc += ef[(size_t)csr_eid[j] * EDIM + c];
    int d = e - s;
    loop_attr[(size_t)n * EDIM + c] = acc / (float)max(d, 1);
}

// ---------------------------------------------------------------------------
// Weight pre-passes
// ---------------------------------------------------------------------------
// W[K][N] fp32 -> transposed bf16 hi/lo [N][K] (for MFMA GEMM)
__global__ void conv_wt(const float* __restrict__ W, unsigned short* __restrict__ hi,
                        unsigned short* __restrict__ lo, int K, int Nn) {
    int idx = blockIdx.x * blockDim.x + threadIdx.x;
    if (idx >= K * Nn) return;
    int k = idx / Nn, n = idx - k * Nn;
    float x = W[idx];
    unsigned short h = f2bf(x);
    unsigned short l = f2bf(x - bf2f(h));
    hi[(size_t)n * K + k] = h;
    lo[(size_t)n * K + k] = l;
}

// We[EDIM][HC] fp32 -> transposed bf16 hi/lo [HC][EDIM] (for score_kernel)
__global__ void conv_wet(const float* __restrict__ We, unsigned short* __restrict__ hi,
                         unsigned short* __restrict__ lo) {
    int idx = blockIdx.x * blockDim.x + threadIdx.x;
    if (idx >= EDIM * HC) return;
    int k = idx / HC, c = idx - k * HC;
    float x = We[idx];
    unsigned short h = f2bf(x);
    unsigned short l = f2bf(x - bf2f(h));
    hi[(size_t)c * EDIM + k] = h;
    lo[(size_t)c * EDIM + k] = l;
}

// ---------------------------------------------------------------------------
// MFMA split-bf16 GEMM: C[M,Nn] = A[M,K] @ B[K,Nn] + bias.
// Optional fused LayerNorm over rows (requires Nn==64, single col-block).
// ---------------------------------------------------------------------------
#define LDT 40

__global__ __launch_bounds__(256, 2)
void gemm_mfma(const float* __restrict__ A, const unsigned short* __restrict__ Bth,
               const unsigned short* __restrict__ Btl, const float* __restrict__ bias,
               float* __restrict__ C, int M, int K, int Nn,
               const float* __restrict__ ln_g, const float* __restrict__ ln_b, int do_ln) {
    __shared__ unsigned short Ah[64][LDT], Al[64][LDT];
    __shared__ unsigned short Bh[64][LDT], Bl[64][LDT];
    int tid = threadIdx.x;
    int lane = tid & 63, w = tid >> 6;
    int m = lane & 15, q = lane >> 4;
    int rowBase = blockIdx.y * 64, colBase = blockIdx.x * 64;
    f32x4 acc[4];
    #pragma unroll
    for (int ct = 0; ct < 4; ct++) acc[ct] = (f32x4){0.f, 0.f, 0.f, 0.f};

    for (int kk = 0; kk < K; kk += 32) {
        #pragma unroll
        for (int u = 0; u < 2; u++) {
            int f = tid + 256 * u;
            int r = f >> 3;
            int k4 = (f & 7) * 4;
            int row = rowBase + r;
            float4 v = make_float4(0.f, 0.f, 0.f, 0.f);
            if (row < M) v = *(const float4*)(A + (size_t)row * K + kk + k4);
            unsigned short h0 = f2bf(v.x), h1 = f2bf(v.y), h2 = f2bf(v.z), h3 = f2bf(v.w);
            unsigned short l0 = f2bf(v.x - bf2f(h0)), l1 = f2bf(v.y - bf2f(h1));
            unsigned short l2 = f2bf(v.z - bf2f(h2)), l3 = f2bf(v.w - bf2f(h3));
            *(u16x4*)&Ah[r][k4] = (u16x4){h0, h1, h2, h3};
            *(u16x4*)&Al[r][k4] = (u16x4){l0, l1, l2, l3};
        }
        {
            int n = tid >> 2;
            int ch = tid & 3;
            size_t goff = (size_t)(colBase + n) * K + kk + ch * 8;
            *(bf16x8*)&Bh[n][ch * 8] = *(const bf16x8*)(Bth + goff);
            *(bf16x8*)&Bl[n][ch * 8] = *(const bf16x8*)(Btl + goff);
        }
        __syncthreads();
        bf16x8 a_h = *(const bf16x8*)&Ah[w * 16 + m][q * 8];
        bf16x8 a_l = *(const bf16x8*)&Al[w * 16 + m][q * 8];
        #pragma unroll
        for (int ct = 0; ct < 4; ct++) {
            bf16x8 b_h = *(const bf16x8*)&Bh[ct * 16 + m][q * 8];
            bf16x8 b_l = *(const bf16x8*)&Bl[ct * 16 + m][q * 8];
            acc[ct] = __builtin_amdgcn_mfma_f32_16x16x32_bf16(a_h, b_h, acc[ct], 0, 0, 0);
            acc[ct] = __builtin_amdgcn_mfma_f32_16x16x32_bf16(a_l, b_h, acc[ct], 0, 0, 0);
            acc[ct] = __builtin_amdgcn_mfma_f32_16x16x32_bf16(a_h, b_l, acc[ct], 0, 0, 0);
        }
        __syncthreads();
    }
    if (!do_ln) {
        #pragma unroll
        for (int ct = 0; ct < 4; ct++) {
            int col = colBase + ct * 16 + m;
            float bb = bias[col];
            #pragma unroll
            for (int r = 0; r < 4; r++) {
                int row = rowBase + w * 16 + q * 4 + r;
                if (row < M) C[(size_t)row * Nn + col] = acc[ct][r] + bb;
            }
        }
    } else {
        // Nn == 64, colBase == 0. Row held by 16 lanes (m) x 4 cols (ct).
        #pragma unroll
        for (int r = 0; r < 4; r++) {
            float v[4];
            float sum = 0.f;
            #pragma unroll
            for (int ct = 0; ct < 4; ct++) {
                v[ct] = acc[ct][r] + bias[ct * 16 + m];
                sum += v[ct];
            }
            sum += __shfl_xor(sum, 1); sum += __shfl_xor(sum, 2);
            sum += __shfl_xor(sum, 4); sum += __shfl_xor(sum, 8);
            float mu = sum * (1.f / 64.f);
            float sq = 0.f;
            #pragma unroll
            for (int ct = 0; ct < 4; ct++) {
                float d = v[ct] - mu;
                sq += d * d;
            }
            sq += __shfl_xor(sq, 1); sq += __shfl_xor(sq, 2);
            sq += __shfl_xor(sq, 4); sq += __shfl_xor(sq, 8);
            float inv = rsqrtf(sq * (1.f / 64.f) + LN_EPS);
            int row = rowBase + w * 16 + q * 4 + r;
            if (row < M) {
                #pragma unroll
                for (int ct = 0; ct < 4; ct++) {
                    int col = ct * 16 + m;
                    C[(size_t)row * 64 + col] = (v[ct] - mu) * inv * ln_g[col] + ln_b[col];
                }
            }
        }
    }
}

// ---------------------------------------------------------------------------
// score_kernel: per 64 CSR slots, ee = ea @ We via 3-term split-bf16 MFMA,
// then fused GATv2 score in the epilogue:
//   alpha[slot][h] = sum_{c in head h} leaky(xl[src]+xr[dst]+ee) * att[h][c]
// C-layout: lane(m,q), reg(ct,r) -> slot = w*16+q*4+r, col = ct*16+m.
// xl/xr gathers are 64B-coalesced per 16-lane m-group.
// ---------------------------------------------------------------------------
__global__ __launch_bounds__(256, 2)
void score_kernel(const float* __restrict__ ef, const float* __restrict__ loop_attr,
                  const int* __restrict__ csr_eid, const int* __restrict__ csr_src,
                  const int* __restrict__ csr_dst,
                  const float* __restrict__ xl, const float* __restrict__ xr,
                  const unsigned short* __restrict__ Weth,
                  const unsigned short* __restrict__ Wetl,
                  const float* __restrict__ att, float* __restrict__ alpha) {
    __shared__ unsigned short Ah[64][LDT], Al[64][LDT];
    __shared__ unsigned short Bh[256][LDT], Bl[256][LDT];
    __shared__ int s_src[64], s_dst[64];
    int tid = threadIdx.x;
    int lane = tid & 63, w = tid >> 6;
    int m = lane & 15, q = lane >> 4;

    // stage B (We^T, [256][32] hi/lo)
    #pragma unroll
    for (int u = 0; u < 4; u++) {
        *(bf16x8*)&Bh[tid][u * 8] = *(const bf16x8*)(Weth + (size_t)tid * EDIM + u * 8);
        *(bf16x8*)&Bl[tid][u * 8] = *(const bf16x8*)(Wetl + (size_t)tid * EDIM + u * 8);
    }
    float attv[16];
    #pragma unroll
    for (int ct = 0; ct < 16; ct++) attv[ct] = att[ct * 16 + m];

    int base = blockIdx.x << 6;
    // stage A: 64 slots x 32 k (gathered), split hi/lo; record src/dst
    {
        int r = tid >> 2, ch = tid & 3;
        int j = base + r;
        if (j >= EESLOTS) j = EESLOTS - 1;
        const float* srcp;
        int ss, dd;
        if (j < NE) {
            srcp = ef + (size_t)csr_eid[j] * EDIM;
            ss = csr_src[j]; dd = csr_dst[j];
        } else {
            int n = j - NE;
            srcp = loop_attr + (size_t)n * EDIM;
            ss = n; dd = n;
        }
        if (ch == 0) { s_src[r] = ss; s_dst[r] = dd; }
        float4 v0 = *(const float4*)(srcp + ch * 8);
        float4 v1 = *(const float4*)(srcp + ch * 8 + 4);
        float vv[8] = {v0.x, v0.y, v0.z, v0.w, v1.x, v1.y, v1.z, v1.w};
        unsigned short hh[8], ll[8];
        #pragma unroll
        for (int i = 0; i < 8; i++) {
            hh[i] = f2bf(vv[i]);
            ll[i] = f2bf(vv[i] - bf2f(hh[i]));
        }
        *(u16x4*)&Ah[r][ch * 8]     = (u16x4){hh[0], hh[1], hh[2], hh[3]};
        *(u16x4*)&Ah[r][ch * 8 + 4] = (u16x4){hh[4], hh[5], hh[6], hh[7]};
        *(u16x4*)&Al[r][ch * 8]     = (u16x4){ll[0], ll[1], ll[2], ll[3]};
        *(u16x4*)&Al[r][ch * 8 + 4] = (u16x4){ll[4], ll[5], ll[6], ll[7]};
    }
    __syncthreads();

    bf16x8 a_h = *(const bf16x8*)&Ah[w * 16 + m][q * 8];
    bf16x8 a_l = *(const bf16x8*)&Al[w * 16 + m][q * 8];
    f32x4 acc[16];
    #pragma unroll
    for (int ct = 0; ct < 16; ct++) {
        bf16x8 b_h = *(const bf16x8*)&Bh[ct * 16 + m][q * 8];
        bf16x8 b_l = *(const bf16x8*)&Bl[ct * 16 + m][q * 8];
        f32x4 c = (f32x4){0.f, 0.f, 0.f, 0.f};
        c = __builtin_amdgcn_mfma_f32_16x16x32_bf16(a_h, b_h, c, 0, 0, 0);
        c = __builtin_amdgcn_mfma_f32_16x16x32_bf16(a_l, b_h, c, 0, 0, 0);
        c = __builtin_amdgcn_mfma_f32_16x16x32_bf16(a_h, b_l, c, 0, 0, 0);
        acc[ct] = c;
    }

    // epilogue: per-slot score
    #pragma unroll
    for (int r = 0; r < 4; r++) {
        int sl = w * 16 + q * 4 + r;
        int slot = base + sl;
        int ss = s_src[sl], dd = s_dst[sl];
        const float* xlr = xl + (size_t)ss * HC + m;
        const float* xrr = xr + (size_t)dd * HC + m;
        float hd[4] = {0.f, 0.f, 0.f, 0.f};
        #pragma unroll
        for (int ct = 0; ct < 16; ct++) {
            float z = xlr[ct * 16] + xrr[ct * 16] + acc[ct][r];
            float lz = fmaxf(z, 0.f) + 0.2f * fminf(z, 0.f);
            hd[ct >> 2] += lz * attv[ct];
        }
        #pragma unroll
        for (int i = 0; i < 4; i++) {
            hd[i] += __shfl_xor(hd[i], 1);
            hd[i] += __shfl_xor(hd[i], 2);
            hd[i] += __shfl_xor(hd[i], 4);
            hd[i] += __shfl_xor(hd[i], 8);
        }
        if (m < 4 && slot < EESLOTS) {
            float v = (m == 0) ? hd[0] : (m == 1) ? hd[1] : (m == 2) ? hd[2] : hd[3];
            alpha[(size_t)slot * 4 + m] = v;
        }
    }
}

// ---------------------------------------------------------------------------
// Lean aggregation: softmax over precomputed alpha (shift = alpha_self,
// mathematically identical to segment-max shift; |alpha| <= ~14 so exp safe),
// weighted gather of xl. One wave per node.
// ---------------------------------------------------------------------------
__global__ __launch_bounds__(256)
void gat_aggr(const float* __restrict__ xl, const float* __restrict__ alpha,
              const int* __restrict__ row_ptr, const int* __restrict__ csr_src,
              const float* __restrict__ bias, float* __restrict__ out, int do_relu) {
    int lane = threadIdx.x & 63;
    int wv = threadIdx.x >> 6;
    int n = blockIdx.x * 4 + wv;
    if (n >= NN) return;
    int h = lane >> 4;
    float4 bb = *(const float4*)(bias + 4 * lane);
    int s0 = row_ptr[n], e0 = row_ptr[n + 1];
    float aself = alpha[(size_t)(NE + n) * 4 + h];
    float denom = 1.f;
    float4 xv = *(const float4*)(xl + (size_t)n * HC + 4 * lane);
    float4 acc = xv;

    for (int j0 = s0; j0 < e0; j0 += 64) {
        int cnt = min(64, e0 - j0);
        int sidx = (j0 + lane < e0) ? csr_src[j0 + lane] : 0;
        int t = 0;
        for (; t + 1 < cnt; t += 2) {
            int sa = __shfl(sidx, t);
            int sb = __shfl(sidx, t + 1);
            float aa = __expf(alpha[(size_t)(j0 + t) * 4 + h] - aself);
            float ab = __expf(alpha[(size_t)(j0 + t + 1) * 4 + h] - aself);
            float4 xa = *(const float4*)(xl + (size_t)sa * HC + 4 * lane);
            float4 xb4 = *(const float4*)(xl + (size_t)sb * HC + 4 * lane);
            denom += aa + ab;
            acc.x += aa * xa.x + ab * xb4.x;
            acc.y += aa * xa.y + ab * xb4.y;
            acc.z += aa * xa.z + ab * xb4.z;
            acc.w += aa * xa.w + ab * xb4.w;
        }
        if (t < cnt) {
            int sa = __shfl(sidx, t);
            float aa = __expf(alpha[(size_t)(j0 + t) * 4 + h] - aself);
            float4 xa = *(const float4*)(xl + (size_t)sa * HC + 4 * lane);
            denom += aa;
            acc.x += aa * xa.x; acc.y += aa * xa.y;
            acc.z += aa * xa.z; acc.w += aa * xa.w;
        }
    }

    float inv = 1.f / denom;
    float4 r = make_float4(acc.x * inv + bb.x, acc.y * inv + bb.y,
                           acc.z * inv + bb.z, acc.w * inv + bb.w);
    if (do_relu) {
        r.x = fmaxf(r.x, 0.f); r.y = fmaxf(r.y, 0.f);
        r.z = fmaxf(r.z, 0.f); r.w = fmaxf(r.w, 0.f);
    }
    *(float4*)(out + (size_t)n * HC + 4 * lane) = r;
}

// ---------------------------------------------------------------------------
// Graph mean pre-reduction exploiting sorted batch
// ---------------------------------------------------------------------------
__global__ void graph_sum(const float* __restrict__ x, const int* __restrict__ batch,
                          float* __restrict__ gsum, float* __restrict__ gcnt) {
    int c = threadIdx.x;
    int r0 = blockIdx.x * 256;
    int r1 = min(r0 + 256, NN);
    float acc = 0.f;
    int gcur = batch[r0];
    for (int n = r0; n < r1; n++) {
        int g = batch[n];
        if (g != gcur) {
            atomicAdd(&gsum[(size_t)gcur * HC + c], acc);
            acc = 0.f; gcur = g;
        }
        acc += x[(size_t)n * HC + c];
    }
    atomicAdd(&gsum[(size_t)gcur * HC + c], acc);
    if (c == 0) {
        int cnt = 0; gcur = batch[r0];
        for (int n = r0; n < r1; n++) {
            int g = batch[n];
            if (g != gcur) {
                atomicAdd(&gcnt[gcur], (float)cnt);
                cnt = 0; gcur = g;
            }
            cnt++;
        }
        atomicAdd(&gcnt[gcur], (float)cnt);
    }
}

__global__ void glob_kernel(const float* __restrict__ gsum, const float* __restrict__ gcnt,
                            const float* __restrict__ W, const float* __restrict__ bias,
                            const float* __restrict__ g, const float* __restrict__ b,
                            float* __restrict__ out) {
    int gi = blockIdx.x;
    int lane = threadIdx.x;
    float inv = 1.f / fmaxf(gcnt[gi], 1.f);
    float acc = 0.f;
    for (int k = 0; k < HC; k++)
        acc += (gsum[(size_t)gi * HC + k] * inv) * W[(size_t)k * ND + lane];
    acc += bias[lane];
    float s = acc;
    #pragma unroll
    for (int o = 32; o >= 1; o >>= 1) s += __shfl_xor(s, o);
    float mu = s * (1.f / 64.f);
    float dv = acc - mu;
    float q = dv * dv;
    #pragma unroll
    for (int o = 32; o >= 1; o >>= 1) q += __shfl_xor(q, o);
    float var = q * (1.f / 64.f);
    out[(size_t)gi * ND + lane] = dv * rsqrtf(var + LN_EPS) * g[lane] + b[lane];
}

// ---------------------------------------------------------------------------
extern "C" void kernel_launch(void* const* d_in, const int* in_sizes, int n_in,
                              void* d_out, int out_size, void* d_ws, size_t ws_size,
                              hipStream_t stream) {
    (void)in_sizes; (void)n_in; (void)out_size; (void)ws_size;
    const float* node_feature = (const float*)d_in[0];
    const int*   edge_index   = (const int*)d_in[1];
    const float* edge_feature = (const float*)d_in[2];
    const int*   batch        = (const int*)d_in[3];
    const float* Wl0   = (const float*)d_in[4];
    const float* bl0   = (const float*)d_in[5];
    const float* Wr0   = (const float*)d_in[6];
    const float* br0   = (const float*)d_in[7];
    const float* We0   = (const float*)d_in[8];
    const float* att0  = (const float*)d_in[9];
    const float* bias0 = (const float*)d_in[10];
    const float* Wl1   = (const float*)d_in[11];
    const float* bl1   = (const float*)d_in[12];
    const float* Wr1   = (const float*)d_in[13];
    const float* br1   = (const float*)d_in[14];
    const float* We1   = (const float*)d_in[15];
    const float* att1  = (const float*)d_in[16];
    const float* bias1 = (const float*)d_in[17];
    const float* node_W  = (const float*)d_in[18];
    const float* node_b  = (const float*)d_in[19];
    const float* graph_W = (const float*)d_in[20];
    const float* graph_b = (const float*)d_in[21];
    const float* nn_g = (const float*)d_in[22];
    const float* nn_b = (const float*)d_in[23];
    const float* gn_g = (const float*)d_in[24];
    const float* gn_b = (const float*)d_in[25];

    const int* src = edge_index;
    const int* dst = edge_index + NE;

    char* p = (char*)d_ws;
    auto carve = [&](size_t bytes) {
        char* r = p;
        p += (bytes + 255) & ~(size_t)255;
        return r;
    };
    int*   row_ptr   = (int*)carve((NN + 1) * sizeof(int));
    int*   cursor    = (int*)carve(NN * sizeof(int));
    int*   csr_src   = (int*)carve((size_t)NE * sizeof(int));
    int*   csr_dst   = (int*)carve((size_t)NE * sizeof(int));
    int*   csr_eid   = (int*)carve((size_t)NE * sizeof(int));
    float* loop_attr = (float*)carve((size_t)NN * EDIM * sizeof(float));
    float* xl        = (float*)carve((size_t)NN * HC * sizeof(float));
    float* xr        = (float*)carve((size_t)NN * HC * sizeof(float));
    float* xb        = (float*)carve((size_t)NN * HC * sizeof(float));
    float* alpha     = (float*)carve((size_t)EESLOTS * NH * sizeof(float));
    float* gsum      = (float*)carve((size_t)(NGG * HC + NGG) * sizeof(float));
    float* gcnt      = gsum + (size_t)NGG * HC;
    // bf16 transposed weight buffers (hi/lo)
    unsigned short* wl0h = (unsigned short*)carve((size_t)DIN * HC * 2 * 2);
    unsigned short* wl0l = wl0h + (size_t)DIN * HC;
    unsigned short* wr0h = (unsigned short*)carve((size_t)DIN * HC * 2 * 2);
    unsigned short* wr0l = wr0h + (size_t)DIN * HC;
    unsigned short* wl1h = (unsigned short*)carve((size_t)HC * HC * 2 * 2);
    unsigned short* wl1l = wl1h + (size_t)HC * HC;
    unsigned short* wr1h = (unsigned short*)carve((size_t)HC * HC * 2 * 2);
    unsigned short* wr1l = wr1h + (size_t)HC * HC;
    unsigned short* nwh  = (unsigned short*)carve((size_t)HC * ND * 2 * 2);
    unsigned short* nwl  = nwh + (size_t)HC * ND;
    unsigned short* we0h = (unsigned short*)carve((size_t)EDIM * HC * 2 * 2);
    unsigned short* we0l = we0h + (size_t)EDIM * HC;
    unsigned short* we1h = (unsigned short*)carve((size_t)EDIM * HC * 2 * 2);
    unsigned short* we1l = we1h + (size_t)EDIM * HC;

    hipMemsetAsync(cursor, 0, NN * sizeof(int), stream);
    hipMemsetAsync(gsum, 0, (NGG * HC + NGG) * sizeof(float), stream);

    // CSR + loop_attr + weight conversion (layer-independent)
    count_deg<<<(NE + 255) / 256, 256, 0, stream>>>(dst, cursor);
    scan_deg<<<1, 1024, 0, stream>>>(cursor, row_ptr);
    fill_csr<<<(NE + 255) / 256, 256, 0, stream>>>(src, dst, cursor, csr_src, csr_dst, csr_eid);
    loop_attr_kernel<<<(NN * EDIM + 255) / 256, 256, 0, stream>>>(edge_feature, row_ptr, csr_eid, loop_attr);
    conv_wt<<<(DIN * HC + 255) / 256, 256, 0, stream>>>(Wl0, wl0h, wl0l, DIN, HC);
    conv_wt<<<(DIN * HC + 255) / 256, 256, 0, stream>>>(Wr0, wr0h, wr0l, DIN, HC);
    conv_wt<<<(HC * HC + 255) / 256, 256, 0, stream>>>(Wl1, wl1h, wl1l, HC, HC);
    conv_wt<<<(HC * HC + 255) / 256, 256, 0, stream>>>(Wr1, wr1h, wr1l, HC, HC);
    conv_wt<<<(HC * ND + 255) / 256, 256, 0, stream>>>(node_W, nwh, nwl, HC, ND);
    conv_wet<<<(EDIM * HC + 255) / 256, 256, 0, stream>>>(We0, we0h, we0l);
    conv_wet<<<(EDIM * HC + 255) / 256, 256, 0, stream>>>(We1, we1h, we1l);

    dim3 g256(HC / 64, (NN + 63) / 64);
    int score_grid = (EESLOTS + 63) / 64;
    // Layer 0
    gemm_mfma<<<g256, 256, 0, stream>>>(node_feature, wl0h, wl0l, bl0, xl, NN, DIN, HC, nullptr, nullptr, 0);
    gemm_mfma<<<g256, 256, 0, stream>>>(node_feature, wr0h, wr0l, br0, xr, NN, DIN, HC, nullptr, nullptr, 0);
    score_kernel<<<score_grid, 256, 0, stream>>>(edge_feature, loop_attr, csr_eid, csr_src, csr_dst,
                                                 xl, xr, we0h, we0l, att0, alpha);
    gat_aggr<<<(NN + 3) / 4, 256, 0, stream>>>(xl, alpha, row_ptr, csr_src, bias0, xb, 1);
    // Layer 1
    gemm_mfma<<<g256, 256, 0, stream>>>(xb, wl1h, wl1l, bl1, xl, NN, HC, HC, nullptr, nullptr, 0);
    gemm_mfma<<<g256, 256, 0, stream>>>(xb, wr1h, wr1l, br1, xr, NN, HC, HC, nullptr, nullptr, 0);
    score_kernel<<<score_grid, 256, 0, stream>>>(edge_feature, loop_attr, csr_eid, csr_src, csr_dst,
                                                 xl, xr, we1h, we1l, att1, alpha);
    gat_aggr<<<(NN + 3) / 4, 256, 0, stream>>>(xl, alpha, row_ptr, csr_src, bias1, xb, 0);

    // Heads
    float* out_local = (float*)d_out;
    float* out_glob  = out_local + (size_t)NN * ND;
    dim3 g64(1, (NN + 63) / 64);
    gemm_mfma<<<g64, 256, 0, stream>>>(xb, nwh, nwl, node_b, out_local, NN, HC, ND, nn_g, nn_b, 1);
    graph_sum<<<(NN + 255) / 256, 256, 0, stream>>>(xb, batch, gsum, gcnt);
    glob_kernel<<<NGG, 64, 0, stream>>>(gsum, gcnt, graph_W, graph_b, gn_g, gn_b, out_glob);
}

// Round 7
// 1001.344 us; speedup vs baseline: 1.1293x; 1.0146x over previous
//
#include <hip/hip_runtime.h>
#include <cstdint>
#include <cstddef>

#define NN   50000
#define NE   500000
#define DIN  64
#define EDIM 32
#define NH   4
#define NC   64
#define HC   256   // NH*NC
#define NGG  64
#define ND   64
#define LN_EPS 1e-5f
#define EESLOTS (NE + NN)   // edges + self-loops, CSR-slot order
#define XLR  512            // row stride of fused xl|xr buffer

typedef __attribute__((ext_vector_type(8))) short bf16x8;
typedef __attribute__((ext_vector_type(4))) float f32x4;
typedef __attribute__((ext_vector_type(4))) unsigned short u16x4;

__device__ __forceinline__ unsigned short f2bf(float x) {
    unsigned u = __float_as_uint(x);
    unsigned r = (u + 0x7FFFu + ((u >> 16) & 1u)) >> 16;
    return (unsigned short)r;
}
__device__ __forceinline__ float bf2f(unsigned short h) {
    return __uint_as_float(((unsigned)h) << 16);
}

// ---------------------------------------------------------------------------
// CSR build: degree count -> single-block scan -> fill
// ---------------------------------------------------------------------------
__global__ void count_deg(const int* __restrict__ dst, int* __restrict__ deg) {
    int e = blockIdx.x * blockDim.x + threadIdx.x;
    if (e < NE) atomicAdd(&deg[dst[e]], 1);
}

__global__ void scan_deg(int* __restrict__ cursor, int* __restrict__ row_ptr) {
    __shared__ int sums[1024];
    const int T = 1024;
    const int chunk = (NN + T - 1) / T;  // 49
    int t = threadIdx.x;
    int lo = t * chunk, hi = min(lo + chunk, NN);
    int s = 0;
    for (int i = lo; i < hi; i++) s += cursor[i];
    sums[t] = s;
    __syncthreads();
    for (int off = 1; off < T; off <<= 1) {
        int v = (t >= off) ? sums[t - off] : 0;
        __syncthreads();
        sums[t] += v;
        __syncthreads();
    }
    int base = (t == 0) ? 0 : sums[t - 1];
    for (int i = lo; i < hi; i++) {
        int d = cursor[i];
        row_ptr[i] = base;
        cursor[i] = base;
        base += d;
    }
    if (t == 0) row_ptr[NN] = NE;
}

__global__ void fill_csr(const int* __restrict__ src, const int* __restrict__ dst,
                         int* __restrict__ cursor, int* __restrict__ csr_src,
                         int* __restrict__ csr_dst, int* __restrict__ csr_eid) {
    int e = blockIdx.x * blockDim.x + threadIdx.x;
    if (e < NE) {
        int d = dst[e];
        int pos = atomicAdd(&cursor[d], 1);
        csr_src[pos] = src[e];
        csr_dst[pos] = d;
        csr_eid[pos] = e;
    }
}

__global__ void loop_attr_kernel(const float* __restrict__ ef, const int* __restrict__ row_ptr,
                                 const int* __restrict__ csr_eid, float* __restrict__ loop_attr) {
    int idx = blockIdx.x * blockDim.x + threadIdx.x;
    if (idx >= NN * EDIM) return;
    int n = idx >> 5, c = idx & 31;
    int s = row_ptr[n], e = row_ptr[n + 1];
    float acc = 0.f;
    for (int j = s; j < e; j++) acc += ef[(size_t)csr_eid[j] * EDIM + c];
    int d = e - s;
    loop_attr[(size_t)n * EDIM + c] = acc / (float)max(d, 1);
}

// ---------------------------------------------------------------------------
// Weight pre-passes
// ---------------------------------------------------------------------------
// W[K][N] fp32 -> transposed bf16 hi/lo [N][K] (for MFMA GEMM)
__global__ void conv_wt(const float* __restrict__ W, unsigned short* __restrict__ hi,
                        unsigned short* __restrict__ lo, int K, int Nn) {
    int idx = blockIdx.x * blockDim.x + threadIdx.x;
    if (idx >= K * Nn) return;
    int k = idx / Nn, n = idx - k * Nn;
    float x = W[idx];
    unsigned short h = f2bf(x);
    unsigned short l = f2bf(x - bf2f(h));
    hi[(size_t)n * K + k] = h;
    lo[(size_t)n * K + k] = l;
}

// We[EDIM][HC] fp32 -> transposed bf16 hi/lo [HC][EDIM] (for score_kernel)
__global__ void conv_wet(const float* __restrict__ We, unsigned short* __restrict__ hi,
                         unsigned short* __restrict__ lo) {
    int idx = blockIdx.x * blockDim.x + threadIdx.x;
    if (idx >= EDIM * HC) return;
    int k = idx / HC, c = idx - k * HC;
    float x = We[idx];
    unsigned short h = f2bf(x);
    unsigned short l = f2bf(x - bf2f(h));
    hi[(size_t)c * EDIM + k] = h;
    lo[(size_t)c * EDIM + k] = l;
}

__global__ void concat_bias(const float* __restrict__ a, const float* __restrict__ b,
                            float* __restrict__ o) {
    int i = threadIdx.x;
    o[i] = a[i];
    o[i + HC] = b[i];
}

#define LDT 40

// ---------------------------------------------------------------------------
// Wide fused GEMM: C[M,512] = A[M,K] @ [Wl|Wr] + [bl|br].  Tile 64x128,
// 256 threads, 8 16x16 col-tiles per wave row-group. 3-term split-bf16.
// Output row stride XLR=512 (xl = cols 0..255, xr = cols 256..511).
// ---------------------------------------------------------------------------
__global__ __launch_bounds__(256, 2)
void gemm_wide(const float* __restrict__ A, const unsigned short* __restrict__ Bth,
               const unsigned short* __restrict__ Btl, const float* __restrict__ bias,
               float* __restrict__ C, int M, int K) {
    __shared__ unsigned short Ah[64][LDT], Al[64][LDT];
    __shared__ unsigned short Bh[128][LDT], Bl[128][LDT];
    int tid = threadIdx.x;
    int lane = tid & 63, w = tid >> 6;
    int m = lane & 15, q = lane >> 4;
    int rowBase = blockIdx.y * 64, colBase = blockIdx.x * 128;
    f32x4 acc[8];
    #pragma unroll
    for (int ct = 0; ct < 8; ct++) acc[ct] = (f32x4){0.f, 0.f, 0.f, 0.f};

    for (int kk = 0; kk < K; kk += 32) {
        // ---- stage A: 64 rows x 32 k fp32 -> hi/lo bf16 (2 float4 / thread)
        #pragma unroll
        for (int u = 0; u < 2; u++) {
            int f = tid + 256 * u;
            int r = f >> 3;
            int k4 = (f & 7) * 4;
            int row = rowBase + r;
            float4 v = make_float4(0.f, 0.f, 0.f, 0.f);
            if (row < M) v = *(const float4*)(A + (size_t)row * K + kk + k4);
            unsigned short h0 = f2bf(v.x), h1 = f2bf(v.y), h2 = f2bf(v.z), h3 = f2bf(v.w);
            unsigned short l0 = f2bf(v.x - bf2f(h0)), l1 = f2bf(v.y - bf2f(h1));
            unsigned short l2 = f2bf(v.z - bf2f(h2)), l3 = f2bf(v.w - bf2f(h3));
            *(u16x4*)&Ah[r][k4] = (u16x4){h0, h1, h2, h3};
            *(u16x4*)&Al[r][k4] = (u16x4){l0, l1, l2, l3};
        }
        // ---- stage B: 128 rows x 32 k bf16 hi/lo (2 chunks / thread)
        #pragma unroll
        for (int u = 0; u < 2; u++) {
            int f = tid + 256 * u;
            int n = f >> 2;
            int ch = f & 3;
            size_t goff = (size_t)(colBase + n) * K + kk + ch * 8;
            *(bf16x8*)&Bh[n][ch * 8] = *(const bf16x8*)(Bth + goff);
            *(bf16x8*)&Bl[n][ch * 8] = *(const bf16x8*)(Btl + goff);
        }
        __syncthreads();
        bf16x8 a_h = *(const bf16x8*)&Ah[w * 16 + m][q * 8];
        bf16x8 a_l = *(const bf16x8*)&Al[w * 16 + m][q * 8];
        #pragma unroll
        for (int ct = 0; ct < 8; ct++) {
            bf16x8 b_h = *(const bf16x8*)&Bh[ct * 16 + m][q * 8];
            bf16x8 b_l = *(const bf16x8*)&Bl[ct * 16 + m][q * 8];
            acc[ct] = __builtin_amdgcn_mfma_f32_16x16x32_bf16(a_h, b_h, acc[ct], 0, 0, 0);
            acc[ct] = __builtin_amdgcn_mfma_f32_16x16x32_bf16(a_l, b_h, acc[ct], 0, 0, 0);
            acc[ct] = __builtin_amdgcn_mfma_f32_16x16x32_bf16(a_h, b_l, acc[ct], 0, 0, 0);
        }
        __syncthreads();
    }
    #pragma unroll
    for (int ct = 0; ct < 8; ct++) {
        int col = colBase + ct * 16 + m;
        float bb = bias[col];
        #pragma unroll
        for (int r = 0; r < 4; r++) {
            int row = rowBase + w * 16 + q * 4 + r;
            if (row < M) C[(size_t)row * XLR + col] = acc[ct][r] + bb;
        }
    }
}

// ---------------------------------------------------------------------------
// MFMA split-bf16 GEMM (64x64) with fused LayerNorm epilogue (Nn==64).
// Used for the local head only.
// ---------------------------------------------------------------------------
__global__ __launch_bounds__(256, 2)
void gemm_head(const float* __restrict__ A, const unsigned short* __restrict__ Bth,
               const unsigned short* __restrict__ Btl, const float* __restrict__ bias,
               float* __restrict__ C, int M, int K,
               const float* __restrict__ ln_g, const float* __restrict__ ln_b) {
    __shared__ unsigned short Ah[64][LDT], Al[64][LDT];
    __shared__ unsigned short Bh[64][LDT], Bl[64][LDT];
    int tid = threadIdx.x;
    int lane = tid & 63, w = tid >> 6;
    int m = lane & 15, q = lane >> 4;
    int rowBase = blockIdx.y * 64;
    f32x4 acc[4];
    #pragma unroll
    for (int ct = 0; ct < 4; ct++) acc[ct] = (f32x4){0.f, 0.f, 0.f, 0.f};

    for (int kk = 0; kk < K; kk += 32) {
        #pragma unroll
        for (int u = 0; u < 2; u++) {
            int f = tid + 256 * u;
            int r = f >> 3;
            int k4 = (f & 7) * 4;
            int row = rowBase + r;
            float4 v = make_float4(0.f, 0.f, 0.f, 0.f);
            if (row < M) v = *(const float4*)(A + (size_t)row * K + kk + k4);
            unsigned short h0 = f2bf(v.x), h1 = f2bf(v.y), h2 = f2bf(v.z), h3 = f2bf(v.w);
            unsigned short l0 = f2bf(v.x - bf2f(h0)), l1 = f2bf(v.y - bf2f(h1));
            unsigned short l2 = f2bf(v.z - bf2f(h2)), l3 = f2bf(v.w - bf2f(h3));
            *(u16x4*)&Ah[r][k4] = (u16x4){h0, h1, h2, h3};
            *(u16x4*)&Al[r][k4] = (u16x4){l0, l1, l2, l3};
        }
        {
            int n = tid >> 2;
            int ch = tid & 3;
            size_t goff = (size_t)n * K + kk + ch * 8;
            *(bf16x8*)&Bh[n][ch * 8] = *(const bf16x8*)(Bth + goff);
            *(bf16x8*)&Bl[n][ch * 8] = *(const bf16x8*)(Btl + goff);
        }
        __syncthreads();
        bf16x8 a_h = *(const bf16x8*)&Ah[w * 16 + m][q * 8];
        bf16x8 a_l = *(const bf16x8*)&Al[w * 16 + m][q * 8];
        #pragma unroll
        for (int ct = 0; ct < 4; ct++) {
            bf16x8 b_h = *(const bf16x8*)&Bh[ct * 16 + m][q * 8];
            bf16x8 b_l = *(const bf16x8*)&Bl[ct * 16 + m][q * 8];
            acc[ct] = __builtin_amdgcn_mfma_f32_16x16x32_bf16(a_h, b_h, acc[ct], 0, 0, 0);
            acc[ct] = __builtin_amdgcn_mfma_f32_16x16x32_bf16(a_l, b_h, acc[ct], 0, 0, 0);
            acc[ct] = __builtin_amdgcn_mfma_f32_16x16x32_bf16(a_h, b_l, acc[ct], 0, 0, 0);
        }
        __syncthreads();
    }
    // LN epilogue: row held by 16 lanes (m) x 4 cols (ct)
    #pragma unroll
    for (int r = 0; r < 4; r++) {
        float v[4];
        float sum = 0.f;
        #pragma unroll
        for (int ct = 0; ct < 4; ct++) {
            v[ct] = acc[ct][r] + bias[ct * 16 + m];
            sum += v[ct];
        }
        sum += __shfl_xor(sum, 1); sum += __shfl_xor(sum, 2);
        sum += __shfl_xor(sum, 4); sum += __shfl_xor(sum, 8);
        float mu = sum * (1.f / 64.f);
        float sq = 0.f;
        #pragma unroll
        for (int ct = 0; ct < 4; ct++) {
            float d = v[ct] - mu;
            sq += d * d;
        }
        sq += __shfl_xor(sq, 1); sq += __shfl_xor(sq, 2);
        sq += __shfl_xor(sq, 4); sq += __shfl_xor(sq, 8);
        float inv = rsqrtf(sq * (1.f / 64.f) + LN_EPS);
        int row = rowBase + w * 16 + q * 4 + r;
        if (row < M) {
            #pragma unroll
            for (int ct = 0; ct < 4; ct++) {
                int col = ct * 16 + m;
                C[(size_t)row * 64 + col] = (v[ct] - mu) * inv * ln_g[col] + ln_b[col];
            }
        }
    }
}

// ---------------------------------------------------------------------------
// score_kernel (persistent): per 64-slot group, ee = ea @ We via split-bf16
// MFMA, fused GATv2 score epilogue -> alpha[slot][h]. We^T staged ONCE per
// block; blocks loop over slot groups (grid-stride).
// ---------------------------------------------------------------------------
__global__ __launch_bounds__(256, 2)
void score_kernel(const float* __restrict__ ef, const float* __restrict__ loop_attr,
                  const int* __restrict__ csr_eid, const int* __restrict__ csr_src,
                  const int* __restrict__ csr_dst,
                  const float* __restrict__ xlr,
                  const unsigned short* __restrict__ Weth,
                  const unsigned short* __restrict__ Wetl,
                  const float* __restrict__ att, float* __restrict__ alpha) {
    __shared__ unsigned short Ah[64][LDT], Al[64][LDT];
    __shared__ unsigned short Bh[256][LDT], Bl[256][LDT];
    __shared__ int s_src[64], s_dst[64];
    int tid = threadIdx.x;
    int lane = tid & 63, w = tid >> 6;
    int m = lane & 15, q = lane >> 4;

    // stage B (We^T, [256][32] hi/lo) ONCE
    #pragma unroll
    for (int u = 0; u < 4; u++) {
        *(bf16x8*)&Bh[tid][u * 8] = *(const bf16x8*)(Weth + (size_t)tid * EDIM + u * 8);
        *(bf16x8*)&Bl[tid][u * 8] = *(const bf16x8*)(Wetl + (size_t)tid * EDIM + u * 8);
    }
    float attv[16];
    #pragma unroll
    for (int ct = 0; ct < 16; ct++) attv[ct] = att[ct * 16 + m];

    int groups = (EESLOTS + 63) >> 6;
    for (int g = blockIdx.x; g < groups; g += gridDim.x) {
        int base = g << 6;
        __syncthreads();   // protect Ah/Al + s_src reads of previous group
        // stage A: 64 slots x 32 k (gathered), split hi/lo; record src/dst
        {
            int r = tid >> 2, ch = tid & 3;
            int j = base + r;
            if (j >= EESLOTS) j = EESLOTS - 1;
            const float* srcp;
            int ss, dd;
            if (j < NE) {
                srcp = ef + (size_t)csr_eid[j] * EDIM;
                ss = csr_src[j]; dd = csr_dst[j];
            } else {
                int n = j - NE;
                srcp = loop_attr + (size_t)n * EDIM;
                ss = n; dd = n;
            }
            if (ch == 0) { s_src[r] = ss; s_dst[r] = dd; }
            float4 v0 = *(const float4*)(srcp + ch * 8);
            float4 v1 = *(const float4*)(srcp + ch * 8 + 4);
            float vv[8] = {v0.x, v0.y, v0.z, v0.w, v1.x, v1.y, v1.z, v1.w};
            unsigned short hh[8], ll[8];
            #pragma unroll
            for (int i = 0; i < 8; i++) {
                hh[i] = f2bf(vv[i]);
                ll[i] = f2bf(vv[i] - bf2f(hh[i]));
            }
            *(u16x4*)&Ah[r][ch * 8]     = (u16x4){hh[0], hh[1], hh[2], hh[3]};
            *(u16x4*)&Ah[r][ch * 8 + 4] = (u16x4){hh[4], hh[5], hh[6], hh[7]};
            *(u16x4*)&Al[r][ch * 8]     = (u16x4){ll[0], ll[1], ll[2], ll[3]};
            *(u16x4*)&Al[r][ch * 8 + 4] = (u16x4){ll[4], ll[5], ll[6], ll[7]};
        }
        __syncthreads();

        bf16x8 a_h = *(const bf16x8*)&Ah[w * 16 + m][q * 8];
        bf16x8 a_l = *(const bf16x8*)&Al[w * 16 + m][q * 8];
        f32x4 acc[16];
        #pragma unroll
        for (int ct = 0; ct < 16; ct++) {
            bf16x8 b_h = *(const bf16x8*)&Bh[ct * 16 + m][q * 8];
            bf16x8 b_l = *(const bf16x8*)&Bl[ct * 16 + m][q * 8];
            f32x4 c = (f32x4){0.f, 0.f, 0.f, 0.f};
            c = __builtin_amdgcn_mfma_f32_16x16x32_bf16(a_h, b_h, c, 0, 0, 0);
            c = __builtin_amdgcn_mfma_f32_16x16x32_bf16(a_l, b_h, c, 0, 0, 0);
            c = __builtin_amdgcn_mfma_f32_16x16x32_bf16(a_h, b_l, c, 0, 0, 0);
            acc[ct] = c;
        }

        // epilogue: per-slot score
        #pragma unroll
        for (int r = 0; r < 4; r++) {
            int sl = w * 16 + q * 4 + r;
            int slot = base + sl;
            int ss = s_src[sl], dd = s_dst[sl];
            const float* xlp = xlr + (size_t)ss * XLR + m;          // xl part
            const float* xrp = xlr + (size_t)dd * XLR + HC + m;     // xr part
            float hd[4] = {0.f, 0.f, 0.f, 0.f};
            #pragma unroll
            for (int ct = 0; ct < 16; ct++) {
                float z = xlp[ct * 16] + xrp[ct * 16] + acc[ct][r];
                float lz = fmaxf(z, 0.f) + 0.2f * fminf(z, 0.f);
                hd[ct >> 2] += lz * attv[ct];
            }
            #pragma unroll
            for (int i = 0; i < 4; i++) {
                hd[i] += __shfl_xor(hd[i], 1);
                hd[i] += __shfl_xor(hd[i], 2);
                hd[i] += __shfl_xor(hd[i], 4);
                hd[i] += __shfl_xor(hd[i], 8);
            }
            if (m < 4 && slot < EESLOTS) {
                float v = (m == 0) ? hd[0] : (m == 1) ? hd[1] : (m == 2) ? hd[2] : hd[3];
                alpha[(size_t)slot * 4 + m] = v;
            }
        }
    }
}

// ---------------------------------------------------------------------------
// Lean aggregation: softmax over precomputed alpha (shift = alpha_self),
// weighted gather of xl (cols 0..255 of xlr). One wave per node, ILP x4.
// ---------------------------------------------------------------------------
__global__ __launch_bounds__(256)
void gat_aggr(const float* __restrict__ xlr, const float* __restrict__ alpha,
              const int* __restrict__ row_ptr, const int* __restrict__ csr_src,
              const float* __restrict__ bias, float* __restrict__ out, int do_relu) {
    int lane = threadIdx.x & 63;
    int wv = threadIdx.x >> 6;
    int n = blockIdx.x * 4 + wv;
    if (n >= NN) return;
    int h = lane >> 4;
    float4 bb = *(const float4*)(bias + 4 * lane);
    int s0 = row_ptr[n], e0 = row_ptr[n + 1];
    float aself = alpha[(size_t)(NE + n) * 4 + h];
    float denom = 1.f;
    float4 acc = *(const float4*)(xlr + (size_t)n * XLR + 4 * lane);

    for (int j0 = s0; j0 < e0; j0 += 64) {
        int cnt = min(64, e0 - j0);
        int sidx = (j0 + lane < e0) ? csr_src[j0 + lane] : 0;
        int t = 0;
        for (; t + 3 < cnt; t += 4) {
            int sa = __shfl(sidx, t);
            int sb = __shfl(sidx, t + 1);
            int sc = __shfl(sidx, t + 2);
            int sd = __shfl(sidx, t + 3);
            float a0 = __expf(alpha[(size_t)(j0 + t) * 4 + h] - aself);
            float a1 = __expf(alpha[(size_t)(j0 + t + 1) * 4 + h] - aself);
            float a2 = __expf(alpha[(size_t)(j0 + t + 2) * 4 + h] - aself);
            float a3 = __expf(alpha[(size_t)(j0 + t + 3) * 4 + h] - aself);
            float4 x0 = *(const float4*)(xlr + (size_t)sa * XLR + 4 * lane);
            float4 x1 = *(const float4*)(xlr + (size_t)sb * XLR + 4 * lane);
            float4 x2 = *(const float4*)(xlr + (size_t)sc * XLR + 4 * lane);
            float4 x3 = *(const float4*)(xlr + (size_t)sd * XLR + 4 * lane);
            denom += a0 + a1 + a2 + a3;
            acc.x += a0 * x0.x + a1 * x1.x + a2 * x2.x + a3 * x3.x;
            acc.y += a0 * x0.y + a1 * x1.y + a2 * x2.y + a3 * x3.y;
            acc.z += a0 * x0.z + a1 * x1.z + a2 * x2.z + a3 * x3.z;
            acc.w += a0 * x0.w + a1 * x1.w + a2 * x2.w + a3 * x3.w;
        }
        for (; t < cnt; t++) {
            int sa = __shfl(sidx, t);
            float a0 = __expf(alpha[(size_t)(j0 + t) * 4 + h] - aself);
            float4 x0 = *(const float4*)(xlr + (size_t)sa * XLR + 4 * lane);
            denom += a0;
            acc.x += a0 * x0.x; acc.y += a0 * x0.y;
            acc.z += a0 * x0.z; acc.w += a0 * x0.w;
        }
    }

    float inv = 1.f / denom;
    float4 r = make_float4(acc.x * inv + bb.x, acc.y * inv + bb.y,
                           acc.z * inv + bb.z, acc.w * inv + bb.w);
    if (do_relu) {
        r.x = fmaxf(r.x, 0.f); r.y = fmaxf(r.y, 0.f);
        r.z = fmaxf(r.z, 0.f); r.w = fmaxf(r.w, 0.f);
    }
    *(float4*)(out + (size_t)n * HC + 4 * lane) = r;
}

// ---------------------------------------------------------------------------
// Graph mean pre-reduction exploiting sorted batch
// ---------------------------------------------------------------------------
__global__ void graph_sum(const float* __restrict__ x, const int* __restrict__ batch,
                          float* __restrict__ gsum, float* __restrict__ gcnt) {
    int c = threadIdx.x;
    int r0 = blockIdx.x * 256;
    int r1 = min(r0 + 256, NN);
    float acc = 0.f;
    int gcur = batch[r0];
    for (int n = r0; n < r1; n++) {
        int g = batch[n];
        if (g != gcur) {
            atomicAdd(&gsum[(size_t)gcur * HC + c], acc);
            acc = 0.f; gcur = g;
        }
        acc += x[(size_t)n * HC + c];
    }
    atomicAdd(&gsum[(size_t)gcur * HC + c], acc);
    if (c == 0) {
        int cnt = 0; gcur = batch[r0];
        for (int n = r0; n < r1; n++) {
            int g = batch[n];
            if (g != gcur) {
                atomicAdd(&gcnt[gcur], (float)cnt);
                cnt = 0; gcur = g;
            }
            cnt++;
        }
        atomicAdd(&gcnt[gcur], (float)cnt);
    }
}

__global__ void glob_kernel(const float* __restrict__ gsum, const float* __restrict__ gcnt,
                            const float* __restrict__ W, const float* __restrict__ bias,
                            const float* __restrict__ g, const float* __restrict__ b,
                            float* __restrict__ out) {
    int gi = blockIdx.x;
    int lane = threadIdx.x;
    float inv = 1.f / fmaxf(gcnt[gi], 1.f);
    float acc = 0.f;
    for (int k = 0; k < HC; k++)
        acc += (gsum[(size_t)gi * HC + k] * inv) * W[(size_t)k * ND + lane];
    acc += bias[lane];
    float s = acc;
    #pragma unroll
    for (int o = 32; o >= 1; o >>= 1) s += __shfl_xor(s, o);
    float mu = s * (1.f / 64.f);
    float dv = acc - mu;
    float q = dv * dv;
    #pragma unroll
    for (int o = 32; o >= 1; o >>= 1) q += __shfl_xor(q, o);
    float var = q * (1.f / 64.f);
    out[(size_t)gi * ND + lane] = dv * rsqrtf(var + LN_EPS) * g[lane] + b[lane];
}

// ---------------------------------------------------------------------------
extern "C" void kernel_launch(void* const* d_in, const int* in_sizes, int n_in,
                              void* d_out, int out_size, void* d_ws, size_t ws_size,
                              hipStream_t stream) {
    (void)in_sizes; (void)n_in; (void)out_size; (void)ws_size;
    const float* node_feature = (const float*)d_in[0];
    const int*   edge_index   = (const int*)d_in[1];
    const float* edge_feature = (const float*)d_in[2];
    const int*   batch        = (const int*)d_in[3];
    const float* Wl0   = (const float*)d_in[4];
    const float* bl0   = (const float*)d_in[5];
    const float* Wr0   = (const float*)d_in[6];
    const float* br0   = (const float*)d_in[7];
    const float* We0   = (const float*)d_in[8];
    const float* att0  = (const float*)d_in[9];
    const float* bias0 = (const float*)d_in[10];
    const float* Wl1   = (const float*)d_in[11];
    const float* bl1   = (const float*)d_in[12];
    const float* Wr1   = (const float*)d_in[13];
    const float* br1   = (const float*)d_in[14];
    const float* We1   = (const float*)d_in[15];
    const float* att1  = (const float*)d_in[16];
    const float* bias1 = (const float*)d_in[17];
    const float* node_W  = (const float*)d_in[18];
    const float* node_b  = (const float*)d_in[19];
    const float* graph_W = (const float*)d_in[20];
    const float* graph_b = (const float*)d_in[21];
    const float* nn_g = (const float*)d_in[22];
    const float* nn_b = (const float*)d_in[23];
    const float* gn_g = (const float*)d_in[24];
    const float* gn_b = (const float*)d_in[25];

    const int* src = edge_index;
    const int* dst = edge_index + NE;

    char* p = (char*)d_ws;
    auto carve = [&](size_t bytes) {
        char* r = p;
        p += (bytes + 255) & ~(size_t)255;
        return r;
    };
    int*   row_ptr   = (int*)carve((NN + 1) * sizeof(int));
    int*   cursor    = (int*)carve(NN * sizeof(int));
    int*   csr_src   = (int*)carve((size_t)NE * sizeof(int));
    int*   csr_dst   = (int*)carve((size_t)NE * sizeof(int));
    int*   csr_eid   = (int*)carve((size_t)NE * sizeof(int));
    float* loop_attr = (float*)carve((size_t)NN * EDIM * sizeof(float));
    float* xlr       = (float*)carve((size_t)NN * XLR * sizeof(float));   // xl|xr fused
    float* xb        = (float*)carve((size_t)NN * HC * sizeof(float));
    float* alpha     = (float*)carve((size_t)EESLOTS * NH * sizeof(float));
    float* gsum      = (float*)carve((size_t)(NGG * HC + NGG) * sizeof(float));
    float* gcnt      = gsum + (size_t)NGG * HC;
    // concat bf16 transposed weights [512][K] hi/lo
    unsigned short* wlr0h = (unsigned short*)carve((size_t)XLR * DIN * 2 * 2);
    unsigned short* wlr0l = wlr0h + (size_t)XLR * DIN;
    unsigned short* wlr1h = (unsigned short*)carve((size_t)XLR * HC * 2 * 2);
    unsigned short* wlr1l = wlr1h + (size_t)XLR * HC;
    unsigned short* nwh   = (unsigned short*)carve((size_t)HC * ND * 2 * 2);
    unsigned short* nwl   = nwh + (size_t)HC * ND;
    unsigned short* we0h  = (unsigned short*)carve((size_t)EDIM * HC * 2 * 2);
    unsigned short* we0l  = we0h + (size_t)EDIM * HC;
    unsigned short* we1h  = (unsigned short*)carve((size_t)EDIM * HC * 2 * 2);
    unsigned short* we1l  = we1h + (size_t)EDIM * HC;
    float* b0cat = (float*)carve(XLR * sizeof(float));
    float* b1cat = (float*)carve(XLR * sizeof(float));

    hipMemsetAsync(cursor, 0, NN * sizeof(int), stream);
    hipMemsetAsync(gsum, 0, (NGG * HC + NGG) * sizeof(float), stream);

    // CSR + loop_attr + weight conversion (layer-independent)
    count_deg<<<(NE + 255) / 256, 256, 0, stream>>>(dst, cursor);
    scan_deg<<<1, 1024, 0, stream>>>(cursor, row_ptr);
    fill_csr<<<(NE + 255) / 256, 256, 0, stream>>>(src, dst, cursor, csr_src, csr_dst, csr_eid);
    loop_attr_kernel<<<(NN * EDIM + 255) / 256, 256, 0, stream>>>(edge_feature, row_ptr, csr_eid, loop_attr);
    conv_wt<<<(DIN * HC + 255) / 256, 256, 0, stream>>>(Wl0, wlr0h, wlr0l, DIN, HC);
    conv_wt<<<(DIN * HC + 255) / 256, 256, 0, stream>>>(Wr0, wlr0h + (size_t)HC * DIN, wlr0l + (size_t)HC * DIN, DIN, HC);
    conv_wt<<<(HC * HC + 255) / 256, 256, 0, stream>>>(Wl1, wlr1h, wlr1l, HC, HC);
    conv_wt<<<(HC * HC + 255) / 256, 256, 0, stream>>>(Wr1, wlr1h + (size_t)HC * HC, wlr1l + (size_t)HC * HC, HC, HC);
    conv_wt<<<(HC * ND + 255) / 256, 256, 0, stream>>>(node_W, nwh, nwl, HC, ND);
    conv_wet<<<(EDIM * HC + 255) / 256, 256, 0, stream>>>(We0, we0h, we0l);
    conv_wet<<<(EDIM * HC + 255) / 256, 256, 0, stream>>>(We1, we1h, we1l);
    concat_bias<<<1, 256, 0, stream>>>(bl0, br0, b0cat);
    concat_bias<<<1, 256, 0, stream>>>(bl1, br1, b1cat);

    dim3 gw(4, (NN + 63) / 64);
    // Layer 0
    gemm_wide<<<gw, 256, 0, stream>>>(node_feature, wlr0h, wlr0l, b0cat, xlr, NN, DIN);
    score_kernel<<<2048, 256, 0, stream>>>(edge_feature, loop_attr, csr_eid, csr_src, csr_dst,
                                           xlr, we0h, we0l, att0, alpha);
    gat_aggr<<<(NN + 3) / 4, 256, 0, stream>>>(xlr, alpha, row_ptr, csr_src, bias0, xb, 1);
    // Layer 1
    gemm_wide<<<gw, 256, 0, stream>>>(xb, wlr1h, wlr1l, b1cat, xlr, NN, HC);
    score_kernel<<<2048, 256, 0, stream>>>(edge_feature, loop_attr, csr_eid, csr_src, csr_dst,
                                           xlr, we1h, we1l, att1, alpha);
    gat_aggr<<<(NN + 3) / 4, 256, 0, stream>>>(xlr, alpha, row_ptr, csr_src, bias1, xb, 0);

    // Heads
    float* out_local = (float*)d_out;
    float* out_glob  = out_local + (size_t)NN * ND;
    dim3 gh(1, (NN + 63) / 64);
    gemm_head<<<gh, 256, 0, stream>>>(xb, nwh, nwl, node_b, out_local, NN, HC, nn_g, nn_b);
    graph_sum<<<(NN + 255) / 256, 256, 0, stream>>>(xb, batch, gsum, gcnt);
    glob_kernel<<<NGG, 64, 0, stream>>>(gsum, gcnt, graph_W, graph_b, gn_g, gn_b, out_glob);
}